// Round 11
// baseline (154.237 us; speedup 1.0000x reference)
//
#include <hip/hip_runtime.h>
#include <math.h>

// QuanvolutionHybridGraphQL:
//   q   = cos(2x2 patches of 28x28 img)            -> (B,196,4)
//   qn  = q / (||q||_2 + 1e-12)
//   fid = (qn . qn^T)^2                             -> (B,196,196)
//   adj = fid>=0.8 ? 1 : fid>=0.5 ? 0.5 : 0 ; diag=0
//   logits = (mean_n q @ W1 + b1) @ W2 + b2         -> (B,10)
// adj 629MB fp32, HBM-write bound. Fill calibrates 6.6 TB/s (~97us floor)
// with PLAIN stores at ~850 waves / long sequential sweeps.
// Ladder: R3 NT 140 | R7 NT aligned 137.5 | R8 -instr null | R9 NT lowocc
// null | R10 plain 2048-blk 148. Theory: plain stores go through L2/L3
// write-back; 2048 interleaved streams defeat its batching (4.2 TB/s);
// NT bypasses caches (insensitive, capped ~4.7). R11 tests the missing
// cell: PLAIN stores x fill-like shape = 512 blocks (2/CU), each block
// sweeps 4 pairs = 1.2MB sequentially; 8-image preamble hoisted upfront.
// Pre-commit: >=135us -> NT@137.5 is the floor, declare roofline.

#define NP    196
#define NPIX  784
#define BLK   256
#define VPR   (NP / 4)            // 49 float4 per row
#define F4PI  (NP * NP / 4)       // 9604 float4 per image
#define F4PP  (2 * F4PI)          // 19208 float4 per image pair
#define PAIRS 4                   // pairs per block (8 images)

typedef float f32x4 __attribute__((ext_vector_type(4)));

__global__ __launch_bounds__(BLK) void quanv_kernel(
    const float* __restrict__ x,
    const float* __restrict__ W1, const float* __restrict__ b1,
    const float* __restrict__ W2, const float* __restrict__ b2,
    float* __restrict__ logits, float* __restrict__ adj)
{
    // qnA starts as raw q, normalized in place. ~50.3KB total.
    __shared__ __align__(16) float qnA[PAIRS][2][NP][4];   // AoS (c-side)
    __shared__ __align__(16) float qnT[PAIRS][2][4][NP];   // dim-major (v-side)
    __shared__ float pooled[8][4];

    const int blk = blockIdx.x;        // 512 blocks, 8 images each
    const int tid = threadIdx.x;
    const int w   = tid >> 6;          // wave 0..3
    const int l   = tid & 63;          // lane 0..63
    const float* imgs = x + (size_t)blk * (8 * NPIX);

    // 1) load 8 images -> cos -> raw q into qnA
    for (int p = tid; p < 8 * NPIX; p += BLK) {
        int im8 = p / NPIX;
        int pp  = p - im8 * NPIX;
        int r = pp / 28;
        int c = pp - r * 28;
        int n  = (r >> 1) * 14 + (c >> 1);
        int dd = ((r & 1) << 1) | (c & 1);
        qnA[im8 >> 1][im8 & 1][n][dd] = cosf(imgs[p]);
    }
    __syncthreads();

    // 2) pooled = mean_n q (raw), wave w handles images 2w, 2w+1
    for (int imw = 0; imw < 2; ++imw) {
        int im8 = 2 * w + imw;
        int pr = im8 >> 1, im = im8 & 1;
        float s0 = 0.f, s1 = 0.f, s2 = 0.f, s3 = 0.f;
        for (int n = l; n < NP; n += 64) {
            s0 += qnA[pr][im][n][0]; s1 += qnA[pr][im][n][1];
            s2 += qnA[pr][im][n][2]; s3 += qnA[pr][im][n][3];
        }
        #pragma unroll
        for (int off = 32; off >= 1; off >>= 1) {
            s0 += __shfl_down(s0, off);
            s1 += __shfl_down(s1, off);
            s2 += __shfl_down(s2, off);
            s3 += __shfl_down(s3, off);
        }
        if (l == 0) {
            pooled[im8][0] = s0 * (1.0f / NP);
            pooled[im8][1] = s1 * (1.0f / NP);
            pooled[im8][2] = s2 * (1.0f / NP);
            pooled[im8][3] = s3 * (1.0f / NP);
        }
    }
    __syncthreads();   // raw q fully read before in-place normalize

    // 3) normalize in place (qnA) + transposed copy (qnT)
    for (int t = tid; t < 8 * NP; t += BLK) {
        int im8 = t / NP;
        int n   = t - im8 * NP;
        int pr = im8 >> 1, im = im8 & 1;
        float a0 = qnA[pr][im][n][0], a1 = qnA[pr][im][n][1];
        float a2 = qnA[pr][im][n][2], a3 = qnA[pr][im][n][3];
        float inv = 1.0f / (sqrtf(a0*a0 + a1*a1 + a2*a2 + a3*a3) + 1e-12f);
        float b0 = a0*inv, b1v = a1*inv, b2v = a2*inv, b3 = a3*inv;
        f32x4 aos; aos.x = b0; aos.y = b1v; aos.z = b2v; aos.w = b3;
        *reinterpret_cast<f32x4*>(&qnA[pr][im][n][0]) = aos;
        qnT[pr][im][0][n] = b0;
        qnT[pr][im][1][n] = b1v;
        qnT[pr][im][2][n] = b2v;
        qnT[pr][im][3][n] = b3;
    }
    __syncthreads();

    // 4) MLP: threads 0..79 (8 images x 10 logits)
    if (tid < 80) {
        int im8 = tid / 10;
        int j   = tid - im8 * 10;
        float p0 = pooled[im8][0], p1 = pooled[im8][1];
        float p2 = pooled[im8][2], p3 = pooled[im8][3];
        float acc = b2[j];
        #pragma unroll
        for (int k = 0; k < 32; ++k) {
            float h = b1[k] + p0 * W1[0*32 + k] + p1 * W1[1*32 + k]
                            + p2 * W1[2*32 + k] + p3 * W1[3*32 + k];
            acc += h * W2[k*10 + j];
        }
        logits[(size_t)(blk * 8 + im8) * 10 + j] = acc;
    }

    // 5) adj: 4 pairs swept sequentially -> block writes 1.2MB contiguous.
    //    PLAIN stores (L2/L3 write-combine path; few streams device-wide).
    for (int k = 0; k < PAIRS; ++k) {
        f32x4* out0 = reinterpret_cast<f32x4*>(adj)
                    + (size_t)(blk * PAIRS + k) * F4PP;
        f32x4* out1 = out0 + F4PI;

        int n   = tid / VPR;
        int m0i = tid - n * VPR;

        for (int e4 = tid; e4 < F4PI; e4 += BLK) {
            const int m0 = m0i * 4;

            f32x4 cA = *reinterpret_cast<const f32x4*>(&qnA[k][0][n][0]);
            f32x4 cB = *reinterpret_cast<const f32x4*>(&qnA[k][1][n][0]);
            f32x4 vA0 = *reinterpret_cast<const f32x4*>(&qnT[k][0][0][m0]);
            f32x4 vA1 = *reinterpret_cast<const f32x4*>(&qnT[k][0][1][m0]);
            f32x4 vA2 = *reinterpret_cast<const f32x4*>(&qnT[k][0][2][m0]);
            f32x4 vA3 = *reinterpret_cast<const f32x4*>(&qnT[k][0][3][m0]);
            f32x4 vB0 = *reinterpret_cast<const f32x4*>(&qnT[k][1][0][m0]);
            f32x4 vB1 = *reinterpret_cast<const f32x4*>(&qnT[k][1][1][m0]);
            f32x4 vB2 = *reinterpret_cast<const f32x4*>(&qnT[k][1][2][m0]);
            f32x4 vB3 = *reinterpret_cast<const f32x4*>(&qnT[k][1][3][m0]);

            f32x4 dA = cA.x*vA0 + cA.y*vA1 + cA.z*vA2 + cA.w*vA3;
            f32x4 dB = cB.x*vB0 + cB.y*vB1 + cB.z*vB2 + cB.w*vB3;
            f32x4 fA = dA * dA;
            f32x4 fB = dB * dB;

            f32x4 oA, oB;
            oA.x = (fA.x >= 0.8f) ? 1.0f : ((fA.x >= 0.5f) ? 0.5f : 0.0f);
            oA.y = (fA.y >= 0.8f) ? 1.0f : ((fA.y >= 0.5f) ? 0.5f : 0.0f);
            oA.z = (fA.z >= 0.8f) ? 1.0f : ((fA.z >= 0.5f) ? 0.5f : 0.0f);
            oA.w = (fA.w >= 0.8f) ? 1.0f : ((fA.w >= 0.5f) ? 0.5f : 0.0f);
            oB.x = (fB.x >= 0.8f) ? 1.0f : ((fB.x >= 0.5f) ? 0.5f : 0.0f);
            oB.y = (fB.y >= 0.8f) ? 1.0f : ((fB.y >= 0.5f) ? 0.5f : 0.0f);
            oB.z = (fB.z >= 0.8f) ? 1.0f : ((fB.z >= 0.5f) ? 0.5f : 0.0f);
            oB.w = (fB.w >= 0.8f) ? 1.0f : ((fB.w >= 0.5f) ? 0.5f : 0.0f);

            bool d0 = (m0 + 0 == n), d1 = (m0 + 1 == n);
            bool d2 = (m0 + 2 == n), d3 = (m0 + 3 == n);
            oA.x = d0 ? 0.0f : oA.x;  oB.x = d0 ? 0.0f : oB.x;
            oA.y = d1 ? 0.0f : oA.y;  oB.y = d1 ? 0.0f : oB.y;
            oA.z = d2 ? 0.0f : oA.z;  oB.z = d2 ? 0.0f : oB.z;
            oA.w = d3 ? 0.0f : oA.w;  oB.w = d3 ? 0.0f : oB.w;

            out0[e4] = oA;
            out1[e4] = oB;

            // e4 += 256  =>  n += 5, m0i += 11 (mod 49)
            m0i += 11;
            n   += 5;
            int wrap = (m0i >= VPR);
            m0i = wrap ? m0i - VPR : m0i;
            n  += wrap;
        }
    }
}

extern "C" void kernel_launch(void* const* d_in, const int* in_sizes, int n_in,
                              void* d_out, int out_size, void* d_ws, size_t ws_size,
                              hipStream_t stream) {
    const float* x  = (const float*)d_in[0];
    const float* W1 = (const float*)d_in[1];
    const float* b1 = (const float*)d_in[2];
    const float* W2 = (const float*)d_in[3];
    const float* b2 = (const float*)d_in[4];

    const int B = in_sizes[0] / NPIX;          // 4096
    float* logits = (float*)d_out;             // B*10
    float* adj    = logits + (size_t)B * 10;   // B*196*196

    quanv_kernel<<<B / 8, BLK, 0, stream>>>(x, W1, b1, W2, b2, logits, adj);
}